// Round 15
// baseline (284.232 us; speedup 1.0000x reference)
//
#include <hip/hip_runtime.h>

// B=4, S=2048, D=768, H=12, E=64, M=B*S=8192, N_qkv=2304
// scale = log2(e)/sqrt(S) folded into Q at QKV-GEMM epilogue (softmax via exp2).
// ROUND-15 = r14 base + attn occupancy combo:
//   VGPR_Count excludes AGPRs: lacc-MFMA version = 84+48 = 132 regs -> 3
//   waves/SIMD (128-reg step) -- why v7's kv-split gained nothing. Fix:
//   (a) lsum via 4 VALU accumulators (r3 form, 76 arch + 32 acc = 108 <= 128,
//       measured perf-neutral vs lacc), (b) kv-split x2 (r7 form, partials +
//       combine) so the unlocked 4th wave/SIMD has blocks to fill.

typedef __bf16 bf16x8 __attribute__((ext_vector_type(8)));
typedef __bf16 bf16x4 __attribute__((ext_vector_type(4)));
typedef float  f32x4  __attribute__((ext_vector_type(4)));
typedef float  f32x16 __attribute__((ext_vector_type(16)));
typedef unsigned u32x4 __attribute__((ext_vector_type(4)));

#define MFMA16(a,b,c) __builtin_amdgcn_mfma_f32_16x16x32_bf16((a),(b),(c),0,0,0)
#define MFMA32(a,b,c) __builtin_amdgcn_mfma_f32_32x32x16_bf16((a),(b),(c),0,0,0)
#define QSCALE2 (0.022097086912079612f * 1.4426950408889634f)

__device__ __forceinline__ void gload16(const void* g, void* l) {
  __builtin_amdgcn_global_load_lds((const __attribute__((address_space(1))) void*)g,
                                   (__attribute__((address_space(3))) void*)l, 16, 0, 0);
}

// ---------------- pack: fp32 -> bf16 (+ weight transposes) ----------------
__global__ __launch_bounds__(256) void pack_kernel(
    const float* __restrict__ x, const float* __restrict__ Wq,
    const float* __restrict__ Wk, const float* __restrict__ Wv,
    const float* __restrict__ Wo,
    __bf16* __restrict__ xb, __bf16* __restrict__ wqkv, __bf16* __restrict__ wot) {
  int tid = blockIdx.x * 256 + threadIdx.x;
  int nth = gridDim.x * 256;
  for (int i = tid; i < 8192 * 768 / 4; i += nth) {
    float4 v = ((const float4*)x)[i];
    bf16x4 o; o[0] = (__bf16)v.x; o[1] = (__bf16)v.y; o[2] = (__bf16)v.z; o[3] = (__bf16)v.w;
    ((bf16x4*)xb)[i] = o;
  }
  for (int i = tid; i < 3 * 768 * 768; i += nth) {
    int n = i / 768, d = i - n * 768;
    int p = n / 768;
    int wn = n - p * 768;
    int h = wn >> 6, e = wn & 63;
    const float* W = (p == 0) ? Wq : (p == 1) ? Wk : Wv;
    wqkv[i] = (__bf16)W[(h * 768 + d) * 64 + e];
  }
  for (int i = tid; i < 768 * 768; i += nth) {
    int n = i / 768, k = i - n * 768;
    wot[i] = (__bf16)Wo[k * 768 + n];
  }
}

// ---- GEMM core v12: 128x128 tile, BK=64, single buffer, 12 K-steps ----------
// BK=64 halves barrier/step count -- the one proven GEMM lever (r12). LDS 32KB
// keeps 3 blocks/CU. 128B rows XOR-swizzled: LDS dest linear, global SOURCE
// pre-swizzled byte^=((row&7)<<4), read col XOR'd identically -> conflict-free.
#define GEMM_CORE(A_, Bt_, m0_, n0_)                                              \
  __shared__ __align__(16) __bf16 As[128 * 64];                                   \
  __shared__ __align__(16) __bf16 Bs[128 * 64];                                   \
  const int tid = threadIdx.x;                                                    \
  const int w = tid >> 6, lane = tid & 63, ln = lane & 15, hi = lane >> 4;        \
  const int wr = w >> 1, wc = w & 1;                                              \
  f32x4 acc[4][4];                                                                \
  {                                                                               \
    f32x4 z = {0.f, 0.f, 0.f, 0.f};                                               \
    _Pragma("unroll") for (int i = 0; i < 4; ++i)                                 \
      _Pragma("unroll") for (int j = 0; j < 4; ++j) acc[i][j] = z;                \
  }                                                                               \
  const int colx0 = ((hi) ^ (ln & 7)) << 4;      /* kk=0 read col (swizzled) */   \
  const int colx1 = ((4 + hi) ^ (ln & 7)) << 4;  /* kk=1 read col (swizzled) */   \
  {                                                                               \
    const int r0 = tid >> 3;                       /* staged row (per 32-group) */\
    const int scb = ((tid & 7) * 16) ^ ((r0 & 7) << 4);  /* pre-swizzled src */   \
    const char* gA = (const char*)(A_) + (size_t)(m0_ + r0) * 1536 + scb;         \
    const char* gB = (const char*)(Bt_) + (size_t)(n0_ + r0) * 1536 + scb;        \
    char* lA = (char*)As + w * 1024;   /* wave-uniform dest (lane*16 implicit) */ \
    char* lB = (char*)Bs + w * 1024;                                              \
    for (int kt = 0; kt < 12; ++kt) {                                             \
      const int kb = kt * 128;                                                    \
      _Pragma("unroll") for (int j = 0; j < 4; ++j) {                             \
        gload16(gA + j * 49152 + kb, lA + j * 4096);                              \
        gload16(gB + j * 49152 + kb, lB + j * 4096);                              \
      }                                                                           \
      __syncthreads();                                                            \
      _Pragma("unroll") for (int kk = 0; kk < 2; ++kk) {                          \
        const int cx = kk ? colx1 : colx0;                                        \
        bf16x8 af[4], bfv[4];                                                     \
        _Pragma("unroll") for (int mt = 0; mt < 4; ++mt)                          \
          af[mt] = *(const bf16x8*)((char*)As + (wr * 64 + mt * 16 + ln) * 128 + cx); \
        _Pragma("unroll") for (int nt = 0; nt < 4; ++nt)                          \
          bfv[nt] = *(const bf16x8*)((char*)Bs + (wc * 64 + nt * 16 + ln) * 128 + cx); \
        _Pragma("unroll") for (int mt = 0; mt < 4; ++mt)                          \
          _Pragma("unroll") for (int nt = 0; nt < 4; ++nt)                        \
            acc[mt][nt] = MFMA16(af[mt], bfv[nt], acc[mt][nt]);                   \
      }                                                                           \
      __syncthreads();                                                            \
    }                                                                             \
  }

__global__ __launch_bounds__(256) void gemm_qkv(
    const __bf16* __restrict__ A, const __bf16* __restrict__ Bt,
    const float* __restrict__ bq, const float* __restrict__ bk,
    const float* __restrict__ bv,
    __bf16* __restrict__ qb, __bf16* __restrict__ kb, __bf16* __restrict__ vt) {
  // T1: XCD-aware bijective swizzle (nwg=1152, 144/XCD)
  const int lin = blockIdx.y * 18 + blockIdx.x;
  const int swzb = (lin & 7) * 144 + (lin >> 3);
  const int m0 = (swzb / 18) * 128, n0 = (swzb % 18) * 128;
  GEMM_CORE(A, Bt, m0, n0)
  const int p = n0 / 768;
  const float* bias = (p == 0) ? bq : (p == 1) ? bk : bv;
  const float sc = (p == 0) ? QSCALE2 : 1.0f;
#pragma unroll
  for (int nt = 0; nt < 4; ++nt) {
    int n = n0 + wc * 64 + nt * 16 + ln;
    int wn = n - p * 768;
    int h = wn >> 6, e = wn & 63;
    float bb = bias[wn];
#pragma unroll
    for (int mt = 0; mt < 4; ++mt) {
      int mrow = m0 + wr * 64 + mt * 16 + hi * 4;
      int b = mrow >> 11, s0 = mrow & 2047;
      if (p == 2) {
        bf16x4 pk;
#pragma unroll
        for (int r = 0; r < 4; ++r) pk[r] = (__bf16)(acc[mt][nt][r] + bb);
        *(bf16x4*)&vt[(((size_t)b * 12 + h) * 64 + e) * 2048 + s0] = pk;
      } else {
        __bf16* dst = (p == 0) ? qb : kb;
#pragma unroll
        for (int r = 0; r < 4; ++r)
          dst[(((size_t)b * 12 + h) * 2048 + s0 + r) * 64 + e] =
              (__bf16)((acc[mt][nt][r] + bb) * sc);
      }
    }
  }
}

// h stored bf16 (halves write), residual from xb (bf16, halves read).
__global__ __launch_bounds__(256) void gemm_proj(
    const __bf16* __restrict__ A, const __bf16* __restrict__ Bt,
    const float* __restrict__ bo, const __bf16* __restrict__ xres,
    __bf16* __restrict__ hout) {
  // T1 swizzle (nwg=384, 48/XCD)
  const int lin = blockIdx.y * 6 + blockIdx.x;
  const int swzb = (lin & 7) * 48 + (lin >> 3);
  const int m0 = (swzb / 6) * 128, n0 = (swzb % 6) * 128;
  GEMM_CORE(A, Bt, m0, n0)
#pragma unroll
  for (int nt = 0; nt < 4; ++nt) {
    int n = n0 + wc * 64 + nt * 16 + ln;
    float bb = bo[n];
#pragma unroll
    for (int mt = 0; mt < 4; ++mt) {
      int mrow = m0 + wr * 64 + mt * 16 + hi * 4;
#pragma unroll
      for (int r = 0; r < 4; ++r) {
        size_t idx = (size_t)(mrow + r) * 768 + n;
        hout[idx] = (__bf16)(acc[mt][nt][r] + bb + (float)xres[idx]);
      }
    }
  }
}

// ------- flash attention v15: r14 tile body + VALU lsum (108 regs) + kv-split
// grid (48, 32): y = qi*2+half; each block does 16 kv-tiles (one half) for 128
// q-rows, writing UNNORMALIZED partials (pc bf16 numerator, pl f32 denom).
// lsum: 4 VALU accumulators (r3 form; saves 24 regs vs lacc-MFMA, perf-neutral)
// -> 76 arch + 32 acc = 108 <= 128 -> 4 waves/SIMD reachable; kv-split grid
// 1536 = 6 blocks/CU gives the 4th wave blocks to occupy (LDS cap 5/CU).
// launch_bounds(256,4) pins the register budget.
__global__ __launch_bounds__(256, 4) void attn_kernel(
    const __bf16* __restrict__ qb, const __bf16* __restrict__ kb,
    const __bf16* __restrict__ vt, __bf16* __restrict__ pc,
    float* __restrict__ pl) {
  __shared__ __align__(16) char lds[32768];
  const int tid = threadIdx.x;
  const int w = tid >> 6, lane = tid & 63;
  const int l31 = lane & 31, h = lane >> 5;
  const int bh = blockIdx.x;
  const int yy = blockIdx.y;
  const int half = yy & 1;
  const int q0 = (yy >> 1) * 128 + w * 32;

  const int o0 = tid * 16, o1 = o0 + 4096;
  const int r0s = o0 >> 7, cb0 = o0 & 127;
  const int r1s = o1 >> 7, cb1 = o1 & 127;
  const char* kgb = (const char*)(kb + (size_t)bh * 2048 * 64) + half * 131072;
  const char* vgb = (const char*)(vt + (size_t)bh * 64 * 2048) + half * 2048;
  const char* ksrc0 = kgb + r0s * 128 + (cb0 ^ ((r0s & 7) << 4));
  const char* ksrc1 = kgb + r1s * 128 + (cb1 ^ ((r1s & 7) << 4));
  const char* vsrc0 = vgb + r0s * 4096 + (cb0 ^ ((r0s & 7) << 4));
  const char* vsrc1 = vgb + r1s * 4096 + (cb1 ^ ((r1s & 7) << 4));
  char* kl0 = lds + w * 1024;
  char* vl0 = lds + 16384 + w * 1024;

#define STAGE(t_, b_) do {                                   \
    gload16(ksrc0 + (size_t)(t_) * 8192, kl0 + (b_) * 8192); \
    gload16(ksrc1 + (size_t)(t_) * 8192, kl0 + (b_) * 8192 + 4096); \
    gload16(vsrc0 + (size_t)(t_) * 128,  vl0 + (b_) * 8192); \
    gload16(vsrc1 + (size_t)(t_) * 128,  vl0 + (b_) * 8192 + 4096); \
  } while (0)

  const __bf16* qp = qb + ((size_t)bh * 2048 + q0 + l31) * 64 + h * 8;
  bf16x8 qf[4];
#pragma unroll
  for (int s = 0; s < 4; ++s) qf[s] = *(const bf16x8*)(qp + 16 * s);

  const int swz = (l31 & 7) << 4;
  const int krd = l31 * 128 + ((h * 16) ^ swz);
  const int vrd = 16384 + l31 * 128 + ((h * 16) ^ swz);
  int ka_[8], va_[8];
#pragma unroll
  for (int kvt = 0; kvt < 2; ++kvt)
#pragma unroll
    for (int s = 0; s < 4; ++s) ka_[kvt * 4 + s] = (krd + kvt * 4096) ^ (s * 32);
#pragma unroll
  for (int ks = 0; ks < 4; ++ks)
#pragma unroll
    for (int et = 0; et < 2; ++et) va_[ks * 2 + et] = (vrd + et * 4096) ^ (ks * 32);

  f32x16 FZ;
#pragma unroll
  for (int r = 0; r < 16; ++r) FZ[r] = 0.f;

  float ls0 = 0.f, ls1 = 0.f, ls2 = 0.f, ls3 = 0.f;
  f32x16 cacc[2];
  cacc[0] = FZ; cacc[1] = FZ;

  STAGE(0, 0);
  __syncthreads();

#define PKPAIR(dst_, i_, ls_)                                                  \
  {                                                                            \
    float pa_ = __builtin_amdgcn_exp2f(sa[2 * (i_)]);                          \
    float pb_ = __builtin_amdgcn_exp2f(sa[2 * (i_) + 1]);                      \
    ls_ += pa_ + pb_;                                                          \
    asm("v_cvt_pk_bf16_f32 %0, %1, %2" : "=v"(dst_) : "v"(pa_), "v"(pb_));     \
  }

#define TILEBODY(B_, T_)                                                       \
  {                                                                            \
    if ((T_) < 15) STAGE((T_) + 1, (B_) ^ 1);                                  \
    bf16x8 kf[2][4], vf[4][2];                                                 \
    _Pragma("unroll") for (int kvt = 0; kvt < 2; ++kvt)                        \
      _Pragma("unroll") for (int s = 0; s < 4; ++s)                            \
        kf[kvt][s] = *(const bf16x8*)(lds + (B_) * 8192 + ka_[kvt * 4 + s]);   \
    _Pragma("unroll") for (int ks = 0; ks < 4; ++ks)                           \
      _Pragma("unroll") for (int et = 0; et < 2; ++et)                         \
        vf[ks][et] = *(const bf16x8*)(lds + (B_) * 8192 + va_[ks * 2 + et]);   \
    u32x4 pau[4];                                                              \
    _Pragma("unroll") for (int kvt = 0; kvt < 2; ++kvt) {                      \
      __builtin_amdgcn_s_setprio(1);                                           \
      f32x16 sa = MFMA32(kf[kvt][0], qf[0], FZ);                               \
      sa = MFMA32(kf[kvt][1], qf[1], sa);                                      \
      sa = MFMA32(kf[kvt][2], qf[2], sa);                                      \
      sa = MFMA32(kf[kvt][3], qf[3], sa);                                      \
      __builtin_amdgcn_s_setprio(0);                                           \
      unsigned c0, c1, c2, c3, c4, c5, c6, c7;                                 \
      PKPAIR(c0, 0, ls0) PKPAIR(c1, 1, ls1) PKPAIR(c2, 2, ls2) PKPAIR(c3, 3, ls3) \
      PKPAIR(c4, 4, ls0) PKPAIR(c5, 5, ls1) PKPAIR(c6, 6, ls2) PKPAIR(c7, 7, ls3) \
      asm("v_permlane32_swap_b32 %0, %1" : "+v"(c0), "+v"(c2));                \
      asm("v_permlane32_swap_b32 %0, %1" : "+v"(c1), "+v"(c3));                \
      asm("v_permlane32_swap_b32 %0, %1" : "+v"(c4), "+v"(c6));                \
      asm("v_permlane32_swap_b32 %0, %1" : "+v"(c5), "+v"(c7));                \
      pau[2 * kvt][0] = c0; pau[2 * kvt][1] = c1;                              \
      pau[2 * kvt][2] = c2; pau[2 * kvt][3] = c3;                              \
      pau[2 * kvt + 1][0] = c4; pau[2 * kvt + 1][1] = c5;                      \
      pau[2 * kvt + 1][2] = c6; pau[2 * kvt + 1][3] = c7;                      \
    }                                                                          \
    __builtin_amdgcn_s_setprio(1);                                             \
    _Pragma("unroll") for (int ks = 0; ks < 4; ++ks) {                         \
      bf16x8 paf = __builtin_bit_cast(bf16x8, pau[ks]);                        \
      cacc[0] = MFMA32(paf, vf[ks][0], cacc[0]);                               \
      cacc[1] = MFMA32(paf, vf[ks][1], cacc[1]);                               \
    }                                                                          \
    __builtin_amdgcn_s_setprio(0);                                             \
    __syncthreads();                                                           \
  }

  for (int t = 0; t < 16; t += 2) {
    TILEBODY(0, t)
    TILEBODY(1, t + 1)
  }
#undef TILEBODY
#undef PKPAIR
#undef STAGE

  // ls partials cover this lane's kv subset; lane halves are complementary.
  float lsum = (ls0 + ls1) + (ls2 + ls3);
  lsum += __shfl_xor(lsum, 32, 64);   // full half-split denom for q = l31
  __bf16* pcH = pc + (size_t)half * 6291456;
  float* plH = pl + half * 98304;
  const int b = bh / 12, hh = bh - b * 12;
  if (h == 0) plH[bh * 2048 + q0 + l31] = lsum;
#pragma unroll
  for (int r = 0; r < 16; ++r) {
    const int ql = (r & 3) + 8 * (r >> 2) + 4 * h;
    size_t base = ((size_t)b * 2048 + q0 + ql) * 768 + hh * 64 + l31;
    pcH[base]      = (__bf16)cacc[0][r];
    pcH[base + 32] = (__bf16)cacc[1][r];
  }
}

// ---------------- combine: ctx = (pc0 + pc1) / (l0 + l1) ----------------
__global__ __launch_bounds__(256) void combine_kernel(
    const __bf16* __restrict__ pc, const float* __restrict__ pl,
    __bf16* __restrict__ ctx) {
  const int i = blockIdx.x * 256 + threadIdx.x;   // 1572864 threads, 4 elems each
  const int base = i * 4;
  const int row = base / 768;
  const int c = base - row * 768;
  const int b = row >> 11, q = row & 2047, h = c >> 6;
  const int lidx = ((b * 12 + h) << 11) + q;
  const float den = pl[lidx] + pl[98304 + lidx];
  const float rl = __builtin_amdgcn_rcpf(den);
  bf16x4 a = *(const bf16x4*)(pc + base);
  bf16x4 d = *(const bf16x4*)(pc + 6291456 + base);
  bf16x4 o;
#pragma unroll
  for (int j = 0; j < 4; ++j) o[j] = (__bf16)(((float)a[j] + (float)d[j]) * rl);
  *(bf16x4*)(ctx + base) = o;
}

// ---------------- LayerNorm over 768 (one row per block, bf16 h) -------------
__global__ __launch_bounds__(256) void ln_kernel(
    const __bf16* __restrict__ hb, const float* __restrict__ gamma,
    const float* __restrict__ beta, float* __restrict__ out) {
  __shared__ float ssum[4], ssq[4];
  const int row = blockIdx.x, t = threadIdx.x;
  const __bf16* hr = hb + (size_t)row * 768;
  float v0 = (float)hr[t], v1 = (float)hr[t + 256], v2 = (float)hr[t + 512];
  float sum = v0 + v1 + v2;
  float sq = v0 * v0 + v1 * v1 + v2 * v2;
#pragma unroll
  for (int mask = 1; mask < 64; mask <<= 1) {
    sum += __shfl_xor(sum, mask, 64);
    sq += __shfl_xor(sq, mask, 64);
  }
  const int w = t >> 6;
  if ((t & 63) == 0) { ssum[w] = sum; ssq[w] = sq; }
  __syncthreads();
  float s1 = ssum[0] + ssum[1] + ssum[2] + ssum[3];
  float s2 = ssq[0] + ssq[1] + ssq[2] + ssq[3];
  float mu = s1 * (1.0f / 768.0f);
  float var = s2 * (1.0f / 768.0f) - mu * mu;
  float rs = rsqrtf(var + 1e-5f);
  float* orow = out + (size_t)row * 768;
  orow[t]       = (v0 - mu) * rs * gamma[t]       + beta[t];
  orow[t + 256] = (v1 - mu) * rs * gamma[t + 256] + beta[t + 256];
  orow[t + 512] = (v2 - mu) * rs * gamma[t + 512] + beta[t + 512];
}

// ---------------- launch ----------------
extern "C" void kernel_launch(void* const* d_in, const int* in_sizes, int n_in,
                              void* d_out, int out_size, void* d_ws, size_t ws_size,
                              hipStream_t stream) {
  const float* x     = (const float*)d_in[0];
  const float* Wq    = (const float*)d_in[1];
  const float* bq    = (const float*)d_in[2];
  const float* Wk    = (const float*)d_in[3];
  const float* bk    = (const float*)d_in[4];
  const float* Wv    = (const float*)d_in[5];
  const float* bv    = (const float*)d_in[6];
  const float* Wo    = (const float*)d_in[7];
  const float* bo    = (const float*)d_in[8];
  const float* gamma = (const float*)d_in[9];
  const float* beta  = (const float*)d_in[10];
  float* out = (float*)d_out;

  char* ws = (char*)d_ws;
  __bf16* xb   = (__bf16*)(ws);                 // 12582912
  __bf16* wqkv = (__bf16*)(ws + 12582912);      //  3538944
  __bf16* wot  = (__bf16*)(ws + 16121856);      //  1179648
  __bf16* qb   = (__bf16*)(ws + 17301504);      // 12582912
  __bf16* kb   = (__bf16*)(ws + 29884416);      // 12582912
  __bf16* vt   = (__bf16*)(ws + 42467328);      // 12582912
  __bf16* ctx  = (__bf16*)(ws + 55050240);      // 12582912
  __bf16* hb   = (__bf16*)(ws + 67633152);      // 12582912 (bf16)
  // attn partials: pc (2x bf16 numerator) aliases hb region + beyond (free
  // until gemm_proj runs, which is after combine); pl appended after.
  __bf16* pc   = (__bf16*)(ws + 67633152);      // 2 x 12582912
  float*  pl   = (float*)(ws + 92798976);       // 2 x 393216

  pack_kernel<<<dim3(1024), dim3(256), 0, stream>>>(x, Wq, Wk, Wv, Wo, xb, wqkv, wot);
  gemm_qkv<<<dim3(18, 64), dim3(256), 0, stream>>>(xb, wqkv, bq, bk, bv, qb, kb, vt);
  attn_kernel<<<dim3(48, 32), dim3(256), 0, stream>>>(qb, kb, vt, pc, pl);
  combine_kernel<<<dim3(6144), dim3(256), 0, stream>>>(pc, pl, ctx);
  gemm_proj<<<dim3(6, 64), dim3(256), 0, stream>>>(ctx, wot, bo, xb, hb);
  ln_kernel<<<dim3(8192), dim3(256), 0, stream>>>(hb, gamma, beta, out);
}

// Round 16
// 157.668 us; speedup vs baseline: 1.8027x; 1.8027x over previous
//
#include <hip/hip_runtime.h>

// B=4, S=2048, D=768, H=12, E=64, M=B*S=8192, N_qkv=2304
// scale = log2(e)/sqrt(S) folded into Q at QKV-GEMM epilogue (softmax via exp2).
// FINAL = round-12/14 best state (158.1us, reproduced 158.2us):
//   - gemm v12: BK=64 single-buffer, XOR-deswizzled LDS, XCD swizzle
//   - attn r4: 32KB LDS / 3 blocks/CU, swapped-QK in-reg P, lsum-MFMA
//   - bf16 h + residual from xb (IO halving, absmax 0.031 < 0.099)
// Refuted levers (counter evidence): attn no-LDS (v5, scatter-bound 186us),
// T15 pingpong (v6, spill), kv-split (v7 reg-capped; v15 forced-occupancy
// spill, WRITE 508MB), KVBLK=128 (v13, occupancy loss); GEMM dbuf (r9
// neutral), small-tile (r10 regress), counted-vmcnt 3-buf (r11 regress).

typedef __bf16 bf16x8 __attribute__((ext_vector_type(8)));
typedef __bf16 bf16x4 __attribute__((ext_vector_type(4)));
typedef float  f32x4  __attribute__((ext_vector_type(4)));
typedef float  f32x16 __attribute__((ext_vector_type(16)));
typedef unsigned u32x4 __attribute__((ext_vector_type(4)));

#define MFMA16(a,b,c) __builtin_amdgcn_mfma_f32_16x16x32_bf16((a),(b),(c),0,0,0)
#define MFMA32(a,b,c) __builtin_amdgcn_mfma_f32_32x32x16_bf16((a),(b),(c),0,0,0)
#define QSCALE2 (0.022097086912079612f * 1.4426950408889634f)

__device__ __forceinline__ void gload16(const void* g, void* l) {
  __builtin_amdgcn_global_load_lds((const __attribute__((address_space(1))) void*)g,
                                   (__attribute__((address_space(3))) void*)l, 16, 0, 0);
}

// ---------------- pack: fp32 -> bf16 (+ weight transposes) ----------------
__global__ __launch_bounds__(256) void pack_kernel(
    const float* __restrict__ x, const float* __restrict__ Wq,
    const float* __restrict__ Wk, const float* __restrict__ Wv,
    const float* __restrict__ Wo,
    __bf16* __restrict__ xb, __bf16* __restrict__ wqkv, __bf16* __restrict__ wot) {
  int tid = blockIdx.x * 256 + threadIdx.x;
  int nth = gridDim.x * 256;
  for (int i = tid; i < 8192 * 768 / 4; i += nth) {
    float4 v = ((const float4*)x)[i];
    bf16x4 o; o[0] = (__bf16)v.x; o[1] = (__bf16)v.y; o[2] = (__bf16)v.z; o[3] = (__bf16)v.w;
    ((bf16x4*)xb)[i] = o;
  }
  for (int i = tid; i < 3 * 768 * 768; i += nth) {
    int n = i / 768, d = i - n * 768;
    int p = n / 768;
    int wn = n - p * 768;
    int h = wn >> 6, e = wn & 63;
    const float* W = (p == 0) ? Wq : (p == 1) ? Wk : Wv;
    wqkv[i] = (__bf16)W[(h * 768 + d) * 64 + e];
  }
  for (int i = tid; i < 768 * 768; i += nth) {
    int n = i / 768, k = i - n * 768;
    wot[i] = (__bf16)Wo[k * 768 + n];
  }
}

// ---- GEMM core v12: 128x128 tile, BK=64, single buffer, 12 K-steps ----------
// BK=64 halves barrier/step count -- the one proven GEMM lever (r12). LDS 32KB
// keeps 3 blocks/CU. 128B rows XOR-swizzled: LDS dest linear, global SOURCE
// pre-swizzled byte^=((row&7)<<4), read col XOR'd identically -> conflict-free.
#define GEMM_CORE(A_, Bt_, m0_, n0_)                                              \
  __shared__ __align__(16) __bf16 As[128 * 64];                                   \
  __shared__ __align__(16) __bf16 Bs[128 * 64];                                   \
  const int tid = threadIdx.x;                                                    \
  const int w = tid >> 6, lane = tid & 63, ln = lane & 15, hi = lane >> 4;        \
  const int wr = w >> 1, wc = w & 1;                                              \
  f32x4 acc[4][4];                                                                \
  {                                                                               \
    f32x4 z = {0.f, 0.f, 0.f, 0.f};                                               \
    _Pragma("unroll") for (int i = 0; i < 4; ++i)                                 \
      _Pragma("unroll") for (int j = 0; j < 4; ++j) acc[i][j] = z;                \
  }                                                                               \
  const int colx0 = ((hi) ^ (ln & 7)) << 4;      /* kk=0 read col (swizzled) */   \
  const int colx1 = ((4 + hi) ^ (ln & 7)) << 4;  /* kk=1 read col (swizzled) */   \
  {                                                                               \
    const int r0 = tid >> 3;                       /* staged row (per 32-group) */\
    const int scb = ((tid & 7) * 16) ^ ((r0 & 7) << 4);  /* pre-swizzled src */   \
    const char* gA = (const char*)(A_) + (size_t)(m0_ + r0) * 1536 + scb;         \
    const char* gB = (const char*)(Bt_) + (size_t)(n0_ + r0) * 1536 + scb;        \
    char* lA = (char*)As + w * 1024;   /* wave-uniform dest (lane*16 implicit) */ \
    char* lB = (char*)Bs + w * 1024;                                              \
    for (int kt = 0; kt < 12; ++kt) {                                             \
      const int kb = kt * 128;                                                    \
      _Pragma("unroll") for (int j = 0; j < 4; ++j) {                             \
        gload16(gA + j * 49152 + kb, lA + j * 4096);                              \
        gload16(gB + j * 49152 + kb, lB + j * 4096);                              \
      }                                                                           \
      __syncthreads();                                                            \
      _Pragma("unroll") for (int kk = 0; kk < 2; ++kk) {                          \
        const int cx = kk ? colx1 : colx0;                                        \
        bf16x8 af[4], bfv[4];                                                     \
        _Pragma("unroll") for (int mt = 0; mt < 4; ++mt)                          \
          af[mt] = *(const bf16x8*)((char*)As + (wr * 64 + mt * 16 + ln) * 128 + cx); \
        _Pragma("unroll") for (int nt = 0; nt < 4; ++nt)                          \
          bfv[nt] = *(const bf16x8*)((char*)Bs + (wc * 64 + nt * 16 + ln) * 128 + cx); \
        _Pragma("unroll") for (int mt = 0; mt < 4; ++mt)                          \
          _Pragma("unroll") for (int nt = 0; nt < 4; ++nt)                        \
            acc[mt][nt] = MFMA16(af[mt], bfv[nt], acc[mt][nt]);                   \
      }                                                                           \
      __syncthreads();                                                            \
    }                                                                             \
  }

__global__ __launch_bounds__(256) void gemm_qkv(
    const __bf16* __restrict__ A, const __bf16* __restrict__ Bt,
    const float* __restrict__ bq, const float* __restrict__ bk,
    const float* __restrict__ bv,
    __bf16* __restrict__ qb, __bf16* __restrict__ kb, __bf16* __restrict__ vt) {
  // T1: XCD-aware bijective swizzle (nwg=1152, 144/XCD)
  const int lin = blockIdx.y * 18 + blockIdx.x;
  const int swzb = (lin & 7) * 144 + (lin >> 3);
  const int m0 = (swzb / 18) * 128, n0 = (swzb % 18) * 128;
  GEMM_CORE(A, Bt, m0, n0)
  const int p = n0 / 768;
  const float* bias = (p == 0) ? bq : (p == 1) ? bk : bv;
  const float sc = (p == 0) ? QSCALE2 : 1.0f;
#pragma unroll
  for (int nt = 0; nt < 4; ++nt) {
    int n = n0 + wc * 64 + nt * 16 + ln;
    int wn = n - p * 768;
    int h = wn >> 6, e = wn & 63;
    float bb = bias[wn];
#pragma unroll
    for (int mt = 0; mt < 4; ++mt) {
      int mrow = m0 + wr * 64 + mt * 16 + hi * 4;
      int b = mrow >> 11, s0 = mrow & 2047;
      if (p == 2) {
        bf16x4 pk;
#pragma unroll
        for (int r = 0; r < 4; ++r) pk[r] = (__bf16)(acc[mt][nt][r] + bb);
        *(bf16x4*)&vt[(((size_t)b * 12 + h) * 64 + e) * 2048 + s0] = pk;
      } else {
        __bf16* dst = (p == 0) ? qb : kb;
#pragma unroll
        for (int r = 0; r < 4; ++r)
          dst[(((size_t)b * 12 + h) * 2048 + s0 + r) * 64 + e] =
              (__bf16)((acc[mt][nt][r] + bb) * sc);
      }
    }
  }
}

// h stored bf16 (halves write), residual from xb (bf16, halves read).
__global__ __launch_bounds__(256) void gemm_proj(
    const __bf16* __restrict__ A, const __bf16* __restrict__ Bt,
    const float* __restrict__ bo, const __bf16* __restrict__ xres,
    __bf16* __restrict__ hout) {
  // T1 swizzle (nwg=384, 48/XCD)
  const int lin = blockIdx.y * 6 + blockIdx.x;
  const int swzb = (lin & 7) * 48 + (lin >> 3);
  const int m0 = (swzb / 6) * 128, n0 = (swzb % 6) * 128;
  GEMM_CORE(A, Bt, m0, n0)
#pragma unroll
  for (int nt = 0; nt < 4; ++nt) {
    int n = n0 + wc * 64 + nt * 16 + ln;
    float bb = bo[n];
#pragma unroll
    for (int mt = 0; mt < 4; ++mt) {
      int mrow = m0 + wr * 64 + mt * 16 + hi * 4;
#pragma unroll
      for (int r = 0; r < 4; ++r) {
        size_t idx = (size_t)(mrow + r) * 768 + n;
        hout[idx] = (__bf16)(acc[mt][nt][r] + bb + (float)xres[idx]);
      }
    }
  }
}

// ---------------- flash attention: 32x32 MFMA, in-register P, swizzled LDS ----
// Best measured: 69us. grid (48,16): block = (b*12+h, 128 q). 4 waves x 32 q.
// KVBLK=64, dbuf 32KB LDS, 3 blocks/CU. Swapped mfma(K,Q): lane (q=lane&31,
// h=lane>>5) holds P[q][kv=(r&3)+8*(r>>2)+4h]; cvt_pk + permlane32_swap builds
// PV A-frags in-register; lsum via MFMA(P,ones). K/V XOR-swizzle
// byte^=((row&7)<<4) with pre-swizzled global source; ^32s col steps.
// XCD = bh%8 via identity blockIdx (hw maps linear id % 8).
__global__ __launch_bounds__(256, 3) void attn_kernel(
    const __bf16* __restrict__ qb, const __bf16* __restrict__ kb,
    const __bf16* __restrict__ vt, __bf16* __restrict__ ctx) {
  __shared__ __align__(16) char lds[32768];
  const int tid = threadIdx.x;
  const int w = tid >> 6, lane = tid & 63;
  const int l31 = lane & 31, h = lane >> 5;
  const int bh = blockIdx.x;
  const int q0 = blockIdx.y * 128 + w * 32;

  const int o0 = tid * 16, o1 = o0 + 4096;
  const int r0s = o0 >> 7, cb0 = o0 & 127;
  const int r1s = o1 >> 7, cb1 = o1 & 127;
  const char* kgb = (const char*)(kb + (size_t)bh * 2048 * 64);
  const char* vgb = (const char*)(vt + (size_t)bh * 64 * 2048);
  const char* ksrc0 = kgb + r0s * 128 + (cb0 ^ ((r0s & 7) << 4));
  const char* ksrc1 = kgb + r1s * 128 + (cb1 ^ ((r1s & 7) << 4));
  const char* vsrc0 = vgb + r0s * 4096 + (cb0 ^ ((r0s & 7) << 4));
  const char* vsrc1 = vgb + r1s * 4096 + (cb1 ^ ((r1s & 7) << 4));
  char* kl0 = lds + w * 1024;
  char* vl0 = lds + 16384 + w * 1024;

#define STAGE(t_, b_) do {                                   \
    gload16(ksrc0 + (size_t)(t_) * 8192, kl0 + (b_) * 8192); \
    gload16(ksrc1 + (size_t)(t_) * 8192, kl0 + (b_) * 8192 + 4096); \
    gload16(vsrc0 + (size_t)(t_) * 128,  vl0 + (b_) * 8192); \
    gload16(vsrc1 + (size_t)(t_) * 128,  vl0 + (b_) * 8192 + 4096); \
  } while (0)

  const __bf16* qp = qb + ((size_t)bh * 2048 + q0 + l31) * 64 + h * 8;
  bf16x8 qf[4];
#pragma unroll
  for (int s = 0; s < 4; ++s) qf[s] = *(const bf16x8*)(qp + 16 * s);

  const int swz = (l31 & 7) << 4;
  const int krd = l31 * 128 + ((h * 16) ^ swz);
  const int vrd = 16384 + l31 * 128 + ((h * 16) ^ swz);
  int ka_[8], va_[8];
#pragma unroll
  for (int kvt = 0; kvt < 2; ++kvt)
#pragma unroll
    for (int s = 0; s < 4; ++s) ka_[kvt * 4 + s] = (krd + kvt * 4096) ^ (s * 32);
#pragma unroll
  for (int ks = 0; ks < 4; ++ks)
#pragma unroll
    for (int et = 0; et < 2; ++et) va_[ks * 2 + et] = (vrd + et * 4096) ^ (ks * 32);

  f32x16 FZ;
#pragma unroll
  for (int r = 0; r < 16; ++r) FZ[r] = 0.f;
  bf16x8 onesf;
#pragma unroll
  for (int j = 0; j < 8; ++j) onesf[j] = (__bf16)1.0f;

  f32x16 lacc = FZ;
  f32x16 cacc[2];
  cacc[0] = FZ; cacc[1] = FZ;

  STAGE(0, 0);
  __syncthreads();

#define PKPAIR(dst_, i_)                                                       \
  {                                                                            \
    float pa_ = __builtin_amdgcn_exp2f(sa[2 * (i_)]);                          \
    float pb_ = __builtin_amdgcn_exp2f(sa[2 * (i_) + 1]);                      \
    asm("v_cvt_pk_bf16_f32 %0, %1, %2" : "=v"(dst_) : "v"(pa_), "v"(pb_));     \
  }

#define TILEBODY(B_, T_)                                                       \
  {                                                                            \
    if ((T_) < 31) STAGE((T_) + 1, (B_) ^ 1);                                  \
    bf16x8 kf[2][4], vf[4][2];                                                 \
    _Pragma("unroll") for (int kvt = 0; kvt < 2; ++kvt)                        \
      _Pragma("unroll") for (int s = 0; s < 4; ++s)                            \
        kf[kvt][s] = *(const bf16x8*)(lds + (B_) * 8192 + ka_[kvt * 4 + s]);   \
    _Pragma("unroll") for (int ks = 0; ks < 4; ++ks)                           \
      _Pragma("unroll") for (int et = 0; et < 2; ++et)                         \
        vf[ks][et] = *(const bf16x8*)(lds + (B_) * 8192 + va_[ks * 2 + et]);   \
    u32x4 pau[4];                                                              \
    _Pragma("unroll") for (int kvt = 0; kvt < 2; ++kvt) {                      \
      __builtin_amdgcn_s_setprio(1);                                           \
      f32x16 sa = MFMA32(kf[kvt][0], qf[0], FZ);                               \
      sa = MFMA32(kf[kvt][1], qf[1], sa);                                      \
      sa = MFMA32(kf[kvt][2], qf[2], sa);                                      \
      sa = MFMA32(kf[kvt][3], qf[3], sa);                                      \
      __builtin_amdgcn_s_setprio(0);                                           \
      unsigned c0, c1, c2, c3, c4, c5, c6, c7;                                 \
      PKPAIR(c0, 0) PKPAIR(c1, 1) PKPAIR(c2, 2) PKPAIR(c3, 3)                  \
      PKPAIR(c4, 4) PKPAIR(c5, 5) PKPAIR(c6, 6) PKPAIR(c7, 7)                  \
      asm("v_permlane32_swap_b32 %0, %1" : "+v"(c0), "+v"(c2));                \
      asm("v_permlane32_swap_b32 %0, %1" : "+v"(c1), "+v"(c3));                \
      asm("v_permlane32_swap_b32 %0, %1" : "+v"(c4), "+v"(c6));                \
      asm("v_permlane32_swap_b32 %0, %1" : "+v"(c5), "+v"(c7));                \
      pau[2 * kvt][0] = c0; pau[2 * kvt][1] = c1;                              \
      pau[2 * kvt][2] = c2; pau[2 * kvt][3] = c3;                              \
      pau[2 * kvt + 1][0] = c4; pau[2 * kvt + 1][1] = c5;                      \
      pau[2 * kvt + 1][2] = c6; pau[2 * kvt + 1][3] = c7;                      \
      lacc = MFMA32(__builtin_bit_cast(bf16x8, pau[2 * kvt]), onesf, lacc);    \
      lacc = MFMA32(__builtin_bit_cast(bf16x8, pau[2 * kvt + 1]), onesf, lacc);\
    }                                                                          \
    __builtin_amdgcn_s_setprio(1);                                             \
    _Pragma("unroll") for (int ks = 0; ks < 4; ++ks) {                         \
      bf16x8 paf = __builtin_bit_cast(bf16x8, pau[ks]);                        \
      cacc[0] = MFMA32(paf, vf[ks][0], cacc[0]);                               \
      cacc[1] = MFMA32(paf, vf[ks][1], cacc[1]);                               \
    }                                                                          \
    __builtin_amdgcn_s_setprio(0);                                             \
    __syncthreads();                                                           \
  }

  for (int t = 0; t < 32; t += 2) {
    TILEBODY(0, t)
    TILEBODY(1, t + 1)
  }
#undef TILEBODY
#undef PKPAIR
#undef STAGE

  const int b = bh / 12, hh = bh - b * 12;
#pragma unroll
  for (int r = 0; r < 16; ++r) {
    const int ql = (r & 3) + 8 * (r >> 2) + 4 * h;
    float rl = __builtin_amdgcn_rcpf(lacc[r]);
    size_t base = ((size_t)b * 2048 + q0 + ql) * 768 + hh * 64 + l31;
    ctx[base]      = (__bf16)(cacc[0][r] * rl);
    ctx[base + 32] = (__bf16)(cacc[1][r] * rl);
  }
}

// ---------------- LayerNorm over 768 (one row per block, bf16 h) -------------
__global__ __launch_bounds__(256) void ln_kernel(
    const __bf16* __restrict__ hb, const float* __restrict__ gamma,
    const float* __restrict__ beta, float* __restrict__ out) {
  __shared__ float ssum[4], ssq[4];
  const int row = blockIdx.x, t = threadIdx.x;
  const __bf16* hr = hb + (size_t)row * 768;
  float v0 = (float)hr[t], v1 = (float)hr[t + 256], v2 = (float)hr[t + 512];
  float sum = v0 + v1 + v2;
  float sq = v0 * v0 + v1 * v1 + v2 * v2;
#pragma unroll
  for (int mask = 1; mask < 64; mask <<= 1) {
    sum += __shfl_xor(sum, mask, 64);
    sq += __shfl_xor(sq, mask, 64);
  }
  const int w = t >> 6;
  if ((t & 63) == 0) { ssum[w] = sum; ssq[w] = sq; }
  __syncthreads();
  float s1 = ssum[0] + ssum[1] + ssum[2] + ssum[3];
  float s2 = ssq[0] + ssq[1] + ssq[2] + ssq[3];
  float mu = s1 * (1.0f / 768.0f);
  float var = s2 * (1.0f / 768.0f) - mu * mu;
  float rs = rsqrtf(var + 1e-5f);
  float* orow = out + (size_t)row * 768;
  orow[t]       = (v0 - mu) * rs * gamma[t]       + beta[t];
  orow[t + 256] = (v1 - mu) * rs * gamma[t + 256] + beta[t + 256];
  orow[t + 512] = (v2 - mu) * rs * gamma[t + 512] + beta[t + 512];
}

// ---------------- launch ----------------
extern "C" void kernel_launch(void* const* d_in, const int* in_sizes, int n_in,
                              void* d_out, int out_size, void* d_ws, size_t ws_size,
                              hipStream_t stream) {
  const float* x     = (const float*)d_in[0];
  const float* Wq    = (const float*)d_in[1];
  const float* bq    = (const float*)d_in[2];
  const float* Wk    = (const float*)d_in[3];
  const float* bk    = (const float*)d_in[4];
  const float* Wv    = (const float*)d_in[5];
  const float* bv    = (const float*)d_in[6];
  const float* Wo    = (const float*)d_in[7];
  const float* bo    = (const float*)d_in[8];
  const float* gamma = (const float*)d_in[9];
  const float* beta  = (const float*)d_in[10];
  float* out = (float*)d_out;

  char* ws = (char*)d_ws;
  __bf16* xb   = (__bf16*)(ws);                 // 12582912
  __bf16* wqkv = (__bf16*)(ws + 12582912);      //  3538944
  __bf16* wot  = (__bf16*)(ws + 16121856);      //  1179648
  __bf16* qb   = (__bf16*)(ws + 17301504);      // 12582912
  __bf16* kb   = (__bf16*)(ws + 29884416);      // 12582912
  __bf16* vt   = (__bf16*)(ws + 42467328);      // 12582912
  __bf16* ctx  = (__bf16*)(ws + 55050240);      // 12582912
  __bf16* hb   = (__bf16*)(ws + 67633152);      // 12582912 (bf16)

  pack_kernel<<<dim3(1024), dim3(256), 0, stream>>>(x, Wq, Wk, Wv, Wo, xb, wqkv, wot);
  gemm_qkv<<<dim3(18, 64), dim3(256), 0, stream>>>(xb, wqkv, bq, bk, bv, qb, kb, vt);
  attn_kernel<<<dim3(48, 16), dim3(256), 0, stream>>>(qb, kb, vt, ctx);
  gemm_proj<<<dim3(6, 64), dim3(256), 0, stream>>>(ctx, wot, bo, xb, hb);
  ln_kernel<<<dim3(8192), dim3(256), 0, stream>>>(hb, gamma, beta, out);
}